// Round 1
// baseline (2434.754 us; speedup 1.0000x reference)
//
#include <hip/hip_runtime.h>
#include <math.h>

#define BS 4096
#define FD 768
#define PD 500
#define ZD 300
#define RNUM 10

// GEMM tile config: 256 threads, 16x16, each thread 8 rows x 4 cols
#define BM 128
#define BN 64
#define BK 16
#define TM 8
#define TN 4

// ---------------------------------------------------------------------------
// Generic tiled fp32 GEMM: C[M,N] = act(A[M,K] @ W[N,K]^T + bias[N])
// ACT: 0 = none, 1 = relu
// ---------------------------------------------------------------------------
template <int ACT>
__global__ __launch_bounds__(256) void gemm_kernel(
    const float* __restrict__ A, const float* __restrict__ W,
    const float* __restrict__ bias, float* __restrict__ C,
    int M, int N, int K) {
  __shared__ float As[BK][BM + 4];
  __shared__ float Bs[BK][BN + 4];
  const int m0 = blockIdx.x * BM;
  const int n0 = blockIdx.y * BN;
  const int tid = threadIdx.x;
  const int tx = tid & 15;
  const int ty = tid >> 4;

  float acc[TM][TN];
#pragma unroll
  for (int i = 0; i < TM; i++)
#pragma unroll
    for (int j = 0; j < TN; j++) acc[i][j] = 0.f;

  const int l_row = tid >> 2;         // 0..63
  const int l_k4 = (tid & 3) * 4;     // 0,4,8,12

  for (int k0 = 0; k0 < K; k0 += BK) {
    // A tile: 128 rows x 16 k (two 64-row halves)
#pragma unroll
    for (int half = 0; half < 2; ++half) {
      int m = m0 + l_row + half * 64;
      int k = k0 + l_k4;
      float4 v = make_float4(0.f, 0.f, 0.f, 0.f);
      if (m < M) {
        if (k + 4 <= K) {
          v = *(const float4*)(A + (size_t)m * K + k);
        } else {
          float t[4] = {0.f, 0.f, 0.f, 0.f};
          for (int j = 0; j < 4; j++)
            if (k + j < K) t[j] = A[(size_t)m * K + k + j];
          v = make_float4(t[0], t[1], t[2], t[3]);
        }
      }
      As[l_k4 + 0][l_row + half * 64] = v.x;
      As[l_k4 + 1][l_row + half * 64] = v.y;
      As[l_k4 + 2][l_row + half * 64] = v.z;
      As[l_k4 + 3][l_row + half * 64] = v.w;
    }
    // B tile: Bs[k][n] = W[n0+n][k0+k]
    {
      int n = n0 + l_row;
      int k = k0 + l_k4;
      float4 v = make_float4(0.f, 0.f, 0.f, 0.f);
      if (n < N) {
        if (k + 4 <= K) {
          v = *(const float4*)(W + (size_t)n * K + k);
        } else {
          float t[4] = {0.f, 0.f, 0.f, 0.f};
          for (int j = 0; j < 4; j++)
            if (k + j < K) t[j] = W[(size_t)n * K + k + j];
          v = make_float4(t[0], t[1], t[2], t[3]);
        }
      }
      Bs[l_k4 + 0][l_row] = v.x;
      Bs[l_k4 + 1][l_row] = v.y;
      Bs[l_k4 + 2][l_row] = v.z;
      Bs[l_k4 + 3][l_row] = v.w;
    }
    __syncthreads();
#pragma unroll
    for (int k = 0; k < BK; k++) {
      float a[TM], b[TN];
#pragma unroll
      for (int i = 0; i < TM; i++) a[i] = As[k][ty * TM + i];
#pragma unroll
      for (int j = 0; j < TN; j++) b[j] = Bs[k][tx * TN + j];
#pragma unroll
      for (int i = 0; i < TM; i++)
#pragma unroll
        for (int j = 0; j < TN; j++) acc[i][j] += a[i] * b[j];
    }
    __syncthreads();
  }

#pragma unroll
  for (int i = 0; i < TM; i++) {
    int m = m0 + ty * TM + i;
    if (m >= M) continue;
#pragma unroll
    for (int j = 0; j < TN; j++) {
      int n = n0 + tx * TN + j;
      if (n >= N) continue;
      float v = acc[i][j] + bias[n];
      if (ACT == 1) v = fmaxf(v, 0.f);
      C[(size_t)m * N + n] = v;
    }
  }
}

// ---------------------------------------------------------------------------
// Embedding GEMM: unified over 6 (input, weight) groups. Row space:
//   [0,4096)        textual      -> S[0][b] direct
//   [4096,8192)     visual       -> S[1][b] direct
//   [8192,12288)    user         -> S[2][b] direct
//   [12288,53248)   retr_textual -> atomic S[3][b], sample0 rows -> E0[0..9]
//   [53248,94208)   retr_visual  -> atomic S[4][b], sample0 rows -> E0[10..19]
//   [94208,135168)  retr_user    -> atomic S[5][b]
// out val = tanh(row @ W^T + bias). K=768 always, N=500.
// ---------------------------------------------------------------------------
struct EmbedPtrs {
  const float* A[6];
  const float* W[6];
  const float* B[6];
};

__global__ __launch_bounds__(256) void embed_gemm(
    EmbedPtrs p, float* __restrict__ S, float* __restrict__ E0) {
  __shared__ float As[BK][BM + 4];
  __shared__ float Bs[BK][BN + 4];
  const int m0 = blockIdx.x * BM;
  const int n0 = blockIdx.y * BN;

  int g, base;
  if (m0 < 4096) { g = 0; base = 0; }
  else if (m0 < 8192) { g = 1; base = 4096; }
  else if (m0 < 12288) { g = 2; base = 8192; }
  else if (m0 < 53248) { g = 3; base = 12288; }
  else if (m0 < 94208) { g = 4; base = 53248; }
  else { g = 5; base = 94208; }

  const float* __restrict__ A = p.A[g] + (size_t)(m0 - base) * FD;
  const float* __restrict__ W = p.W[g];
  const float* __restrict__ bias = p.B[g];

  const int tid = threadIdx.x;
  const int tx = tid & 15;
  const int ty = tid >> 4;

  float acc[TM][TN];
#pragma unroll
  for (int i = 0; i < TM; i++)
#pragma unroll
    for (int j = 0; j < TN; j++) acc[i][j] = 0.f;

  const int l_row = tid >> 2;
  const int l_k4 = (tid & 3) * 4;

  for (int k0 = 0; k0 < FD; k0 += BK) {
#pragma unroll
    for (int half = 0; half < 2; ++half) {
      float4 v = *(const float4*)(A + (size_t)(l_row + half * 64) * FD + k0 + l_k4);
      As[l_k4 + 0][l_row + half * 64] = v.x;
      As[l_k4 + 1][l_row + half * 64] = v.y;
      As[l_k4 + 2][l_row + half * 64] = v.z;
      As[l_k4 + 3][l_row + half * 64] = v.w;
    }
    {
      int n = n0 + l_row;
      float4 v = make_float4(0.f, 0.f, 0.f, 0.f);
      if (n < PD) v = *(const float4*)(W + (size_t)n * FD + k0 + l_k4);
      Bs[l_k4 + 0][l_row] = v.x;
      Bs[l_k4 + 1][l_row] = v.y;
      Bs[l_k4 + 2][l_row] = v.z;
      Bs[l_k4 + 3][l_row] = v.w;
    }
    __syncthreads();
#pragma unroll
    for (int k = 0; k < BK; k++) {
      float a[TM], b[TN];
#pragma unroll
      for (int i = 0; i < TM; i++) a[i] = As[k][ty * TM + i];
#pragma unroll
      for (int j = 0; j < TN; j++) b[j] = Bs[k][tx * TN + j];
#pragma unroll
      for (int i = 0; i < TM; i++)
#pragma unroll
        for (int j = 0; j < TN; j++) acc[i][j] += a[i] * b[j];
    }
    __syncthreads();
  }

#pragma unroll
  for (int i = 0; i < TM; i++) {
    const int r = m0 - base + ty * TM + i;  // row within group
#pragma unroll
    for (int j = 0; j < TN; j++) {
      const int n = n0 + tx * TN + j;
      if (n >= PD) continue;
      float v = tanhf(acc[i][j] + bias[n]);
      if (g < 3) {
        S[((size_t)g * BS + r) * PD + n] = v;
      } else {
        const int b = r / 10;
        const int rr = r - b * 10;
        atomicAdd(&S[((size_t)g * BS + b) * PD + n], v);
        if (b == 0 && g != 5) {
          E0[((size_t)(g - 3) * 10 + rr) * PD + n] = v;
        }
      }
    }
  }
}

// ---------------------------------------------------------------------------
// Edge means: Mn[b*4+e][k], e=0: (t+v+u)/3; e=1: (sum_rt+t)/11;
// e=2: (sum_rv+v)/11; e=3: (sum_ru+u)/11
// ---------------------------------------------------------------------------
__global__ __launch_bounds__(256) void means_kernel(
    const float* __restrict__ S, float* __restrict__ Mn) {
  const int total = 4 * BS * PD;
  for (int i = blockIdx.x * blockDim.x + threadIdx.x; i < total;
       i += gridDim.x * blockDim.x) {
    int m = i / PD;
    int k = i - m * PD;
    int b = m >> 2, e = m & 3;
    float v;
    const size_t o = (size_t)b * PD + k;
    if (e == 0)
      v = (S[o] + S[(size_t)BS * PD + o] + S[2 * (size_t)BS * PD + o]) * (1.f / 3.f);
    else if (e == 1)
      v = (S[3 * (size_t)BS * PD + o] + S[o]) * (1.f / 11.f);
    else if (e == 2)
      v = (S[4 * (size_t)BS * PD + o] + S[(size_t)BS * PD + o]) * (1.f / 11.f);
    else
      v = (S[5 * (size_t)BS * PD + o] + S[2 * (size_t)BS * PD + o]) * (1.f / 11.f);
    Mn[i] = v;
  }
}

// ---------------------------------------------------------------------------
// Sample-0 individual Xt rows: XtE[i][n] = E0[i] @ hg_w[n] + hg_b[n], i<20
// ---------------------------------------------------------------------------
__global__ __launch_bounds__(256) void xte_kernel(
    const float* __restrict__ E0, const float* __restrict__ hg_w,
    const float* __restrict__ hg_b, float* __restrict__ XtE) {
  const int i = blockIdx.x;  // 0..19
  __shared__ float row[PD];
  for (int k = threadIdx.x; k < PD; k += 256) row[k] = E0[(size_t)i * PD + k];
  __syncthreads();
  for (int n = threadIdx.x; n < ZD; n += 256) {
    float s = 0.f;
    const float* w = hg_w + (size_t)n * PD;
    for (int k = 0; k < PD; k++) s += row[k] * w[k];
    XtE[(size_t)i * ZD + n] = s + hg_b[n];
  }
}

// ---------------------------------------------------------------------------
// feat builder: feat[b] = [Xo0, Xo1, Xo2, rv_agg, rt_agg, ru_agg, lbl_emb]
// ---------------------------------------------------------------------------
__global__ __launch_bounds__(256) void feat_kernel(
    const float* __restrict__ Y, const float* __restrict__ XtE,
    const float* __restrict__ sim_in, const float* __restrict__ label,
    const float* __restrict__ lbl_w, const float* __restrict__ lbl_b,
    float* __restrict__ feat) {
  const int b = blockIdx.x;
  __shared__ float w[RNUM];
  __shared__ float lbl_agg_s;
  if (threadIdx.x == 0) {
    float s[RNUM], mx = -1e30f;
    for (int r = 0; r < RNUM; r++) {
      s[r] = sim_in[(size_t)b * RNUM + r];
      mx = fmaxf(mx, s[r]);
    }
    float sum = 0.f;
    for (int r = 0; r < RNUM; r++) { s[r] = expf(s[r] - mx); sum += s[r]; }
    float la = 0.f;
    for (int r = 0; r < RNUM; r++) {
      w[r] = s[r] / sum;
      la += w[r] * label[(size_t)b * RNUM + r];
    }
    lbl_agg_s = la;
  }
  __syncthreads();
  const float* Yb = Y + (size_t)b * 4 * ZD;
  float* fb = feat + (size_t)b * 7 * ZD;
  const float la = lbl_agg_s;
  for (int n = threadIdx.x; n < ZD; n += blockDim.x) {
    float y0 = Yb[n], y1 = Yb[ZD + n], y2 = Yb[2 * ZD + n], y3 = Yb[3 * ZD + n];
    fb[n] = fmaxf(0.5f * (y0 + y1), 0.f);
    fb[ZD + n] = fmaxf(0.5f * (y0 + y2), 0.f);
    fb[2 * ZD + n] = fmaxf(0.5f * (y0 + y3), 0.f);
    float rv, rt;
    if (b == 0) {
      rv = 0.f; rt = 0.f;
      for (int r = 0; r < RNUM; r++) {
        float yp = 0.5f * (XtE[(size_t)r * ZD + n] + XtE[(size_t)(10 + r) * ZD + n]);
        rt += w[r] * fmaxf(0.5f * (y1 + yp), 0.f);
        rv += w[r] * fmaxf(0.5f * (y2 + yp), 0.f);
      }
    } else {
      rt = fmaxf(y1, 0.f);
      rv = fmaxf(y2, 0.f);
    }
    fb[3 * ZD + n] = rv;
    fb[4 * ZD + n] = rt;
    fb[5 * ZD + n] = fmaxf(y3, 0.f);
    fb[6 * ZD + n] = fmaxf(la * lbl_w[n] + lbl_b[n], 0.f);
  }
}

// ---------------------------------------------------------------------------
// Head: out[b] = sigmoid(h2[b] . p3_w + p3_b), one wave per sample
// ---------------------------------------------------------------------------
__global__ __launch_bounds__(256) void head_kernel(
    const float* __restrict__ h2, const float* __restrict__ p3_w,
    const float* __restrict__ p3_b, float* __restrict__ out) {
  const int wave = (blockIdx.x * blockDim.x + threadIdx.x) >> 6;
  const int lane = threadIdx.x & 63;
  if (wave >= BS) return;
  const float* row = h2 + (size_t)wave * 200;
  float s = 0.f;
  for (int k = lane; k < 200; k += 64) s += row[k] * p3_w[k];
#pragma unroll
  for (int off = 32; off; off >>= 1) s += __shfl_down(s, off, 64);
  if (lane == 0) out[wave] = 1.f / (1.f + expf(-(s + p3_b[0])));
}

// ---------------------------------------------------------------------------
extern "C" void kernel_launch(void* const* d_in, const int* in_sizes, int n_in,
                              void* d_out, int out_size, void* d_ws,
                              size_t ws_size, hipStream_t stream) {
  (void)in_sizes; (void)n_in; (void)out_size; (void)ws_size;

  const float* visual = (const float*)d_in[0];
  const float* textual = (const float*)d_in[1];
  const float* similarity = (const float*)d_in[2];
  const float* r_visual = (const float*)d_in[3];
  const float* r_textual = (const float*)d_in[4];
  const float* r_label = (const float*)d_in[5];
  const float* user = (const float*)d_in[6];
  const float* r_user = (const float*)d_in[7];
  // d_in[8] retrieved_user_similarity: softmax weights sum to 1 over an
  // identical vector -> ru_agg == relu(Y3); never needed.
  const float* vis_w = (const float*)d_in[9];
  const float* vis_b = (const float*)d_in[10];
  const float* txt_w = (const float*)d_in[11];
  const float* txt_b = (const float*)d_in[12];
  const float* usr_w = (const float*)d_in[13];
  const float* usr_b = (const float*)d_in[14];
  const float* rvis_w = (const float*)d_in[15];
  const float* rvis_b = (const float*)d_in[16];
  const float* rtxt_w = (const float*)d_in[17];
  const float* rtxt_b = (const float*)d_in[18];
  const float* rusr_w = (const float*)d_in[19];
  const float* rusr_b = (const float*)d_in[20];
  const float* hg_w = (const float*)d_in[21];
  const float* hg_b = (const float*)d_in[22];
  const float* lbl_w = (const float*)d_in[23];
  const float* lbl_b = (const float*)d_in[24];
  const float* p1_w = (const float*)d_in[25];
  const float* p1_b = (const float*)d_in[26];
  const float* p2_w = (const float*)d_in[27];
  const float* p2_b = (const float*)d_in[28];
  const float* p3_w = (const float*)d_in[29];
  const float* p3_b = (const float*)d_in[30];
  float* out = (float*)d_out;

  // workspace layout (floats)
  float* ws = (float*)d_ws;
  float* S = ws;                       // 6*4096*500 = 12,288,000
  float* E0 = S + (size_t)6 * BS * PD; // 20*500
  float* XtE = E0 + 20 * PD;           // 20*300
  float* Mn = XtE + 20 * ZD;           // 16384*500
  float* Y = Mn + (size_t)4 * BS * PD; // 16384*300
  float* feat = Y + (size_t)4 * BS * ZD;  // 4096*2100
  float* h1 = feat + (size_t)BS * 7 * ZD; // 4096*800
  float* h2 = h1 + (size_t)BS * 800;      // 4096*200

  // zero the atomic accumulation region S[3..5]
  hipMemsetAsync(S + (size_t)3 * BS * PD, 0, (size_t)3 * BS * PD * sizeof(float),
                 stream);

  EmbedPtrs ep;
  ep.A[0] = textual;  ep.W[0] = txt_w;  ep.B[0] = txt_b;
  ep.A[1] = visual;   ep.W[1] = vis_w;  ep.B[1] = vis_b;
  ep.A[2] = user;     ep.W[2] = usr_w;  ep.B[2] = usr_b;
  ep.A[3] = r_textual; ep.W[3] = rtxt_w; ep.B[3] = rtxt_b;
  ep.A[4] = r_visual;  ep.W[4] = rvis_w; ep.B[4] = rvis_b;
  ep.A[5] = r_user;    ep.W[5] = rusr_w; ep.B[5] = rusr_b;

  embed_gemm<<<dim3(135168 / BM, (PD + BN - 1) / BN), 256, 0, stream>>>(ep, S, E0);
  xte_kernel<<<20, 256, 0, stream>>>(E0, hg_w, hg_b, XtE);
  means_kernel<<<4096, 256, 0, stream>>>(S, Mn);
  gemm_kernel<0><<<dim3(4 * BS / BM, (ZD + BN - 1) / BN), 256, 0, stream>>>(
      Mn, hg_w, hg_b, Y, 4 * BS, ZD, PD);
  feat_kernel<<<BS, 256, 0, stream>>>(Y, XtE, similarity, r_label, lbl_w, lbl_b,
                                      feat);
  gemm_kernel<1><<<dim3(BS / BM, (800 + BN - 1) / BN), 256, 0, stream>>>(
      feat, p1_w, p1_b, h1, BS, 800, 7 * ZD);
  gemm_kernel<1><<<dim3(BS / BM, (200 + BN - 1) / BN), 256, 0, stream>>>(
      h1, p2_w, p2_b, h2, BS, 200, 800);
  head_kernel<<<BS * 64 / 256, 256, 0, stream>>>(h2, p3_w, p3_b, out);
}

// Round 3
// 1304.164 us; speedup vs baseline: 1.8669x; 1.8669x over previous
//
#include <hip/hip_runtime.h>
#include <math.h>

#define BS 4096
#define FD 768
#define PD 500
#define ZD 300
#define RNUM 10

typedef short bf16x8 __attribute__((ext_vector_type(8)));
typedef float f32x4 __attribute__((ext_vector_type(4)));

__device__ __forceinline__ unsigned int fbits(float f) {
  union { float f; unsigned int u; } v; v.f = f; return v.u;
}

// pack two fp32 -> two bf16 (round-half-up) in one v_perm
__device__ __forceinline__ unsigned int pack2bf(float f0, float f1) {
  unsigned int u0 = fbits(f0) + 0x8000u;
  unsigned int u1 = fbits(f1) + 0x8000u;
  return __builtin_amdgcn_perm(u1, u0, 0x07060302u);
}

// ---------------------------------------------------------------------------
// fp32 tiled GEMM (kept for the small p2 layer): C = act(A@W^T + b)
// ---------------------------------------------------------------------------
#define BM 128
#define BN 64
#define BK 16
#define TM 8
#define TN 4
template <int ACT>
__global__ __launch_bounds__(256) void gemm_kernel(
    const float* __restrict__ A, const float* __restrict__ W,
    const float* __restrict__ bias, float* __restrict__ C,
    int M, int N, int K) {
  __shared__ float As[BK][BM + 4];
  __shared__ float Bs[BK][BN + 4];
  const int m0 = blockIdx.x * BM;
  const int n0 = blockIdx.y * BN;
  const int tid = threadIdx.x;
  const int tx = tid & 15;
  const int ty = tid >> 4;
  float acc[TM][TN];
#pragma unroll
  for (int i = 0; i < TM; i++)
#pragma unroll
    for (int j = 0; j < TN; j++) acc[i][j] = 0.f;
  const int l_row = tid >> 2;
  const int l_k4 = (tid & 3) * 4;
  for (int k0 = 0; k0 < K; k0 += BK) {
#pragma unroll
    for (int half = 0; half < 2; ++half) {
      int m = m0 + l_row + half * 64;
      int k = k0 + l_k4;
      float4 v = make_float4(0.f, 0.f, 0.f, 0.f);
      if (m < M && k + 4 <= K) v = *(const float4*)(A + (size_t)m * K + k);
      As[l_k4 + 0][l_row + half * 64] = v.x;
      As[l_k4 + 1][l_row + half * 64] = v.y;
      As[l_k4 + 2][l_row + half * 64] = v.z;
      As[l_k4 + 3][l_row + half * 64] = v.w;
    }
    {
      int n = n0 + l_row;
      int k = k0 + l_k4;
      float4 v = make_float4(0.f, 0.f, 0.f, 0.f);
      if (n < N && k + 4 <= K) v = *(const float4*)(W + (size_t)n * K + k);
      Bs[l_k4 + 0][l_row] = v.x;
      Bs[l_k4 + 1][l_row] = v.y;
      Bs[l_k4 + 2][l_row] = v.z;
      Bs[l_k4 + 3][l_row] = v.w;
    }
    __syncthreads();
#pragma unroll
    for (int k = 0; k < BK; k++) {
      float a[TM], b[TN];
#pragma unroll
      for (int i = 0; i < TM; i++) a[i] = As[k][ty * TM + i];
#pragma unroll
      for (int j = 0; j < TN; j++) b[j] = Bs[k][tx * TN + j];
#pragma unroll
      for (int i = 0; i < TM; i++)
#pragma unroll
        for (int j = 0; j < TN; j++) acc[i][j] += a[i] * b[j];
    }
    __syncthreads();
  }
#pragma unroll
  for (int i = 0; i < TM; i++) {
    int m = m0 + ty * TM + i;
    if (m >= M) continue;
#pragma unroll
    for (int j = 0; j < TN; j++) {
      int n = n0 + tx * TN + j;
      if (n >= N) continue;
      float v = acc[i][j] + bias[n];
      if (ACT == 1) v = fmaxf(v, 0.f);
      C[(size_t)m * N + n] = v;
    }
  }
}

// ---------------------------------------------------------------------------
// pad-cast fp32 weight [rs,cs] -> bf16 [rd,cd], zero padded
// ---------------------------------------------------------------------------
__global__ __launch_bounds__(256) void padcast(
    const float* __restrict__ src, unsigned short* __restrict__ dst,
    int rs, int cs, int rd, int cd) {
  int i = blockIdx.x * 256 + threadIdx.x;
  if (i >= rd * cd) return;
  int r = i / cd, c = i - r * cd;
  float v = (r < rs && c < cs) ? src[(size_t)r * cs + c] : 0.f;
  dst[i] = (unsigned short)((fbits(v) + 0x8000u) >> 16);
}

// ===========================================================================
// bf16 MFMA GEMM core (128x128 tile, 4 waves of 64x64, BK=32)
// LDS layout: per row (128 rows), 4 granules of 16B; granule kq stored at
// slot (kq ^ ((row>>1)&3)) -> 2-way-only bank aliasing for b128 read/write.
// A is fp32 in global, converted to bf16 during staging. B is pre-cast bf16
// [Npad][Kp] (zero padded), k-major.
// Staging coverage: A = 256 thr x 2 x 16B = 8KB (full tile); B likewise
// (256 thr x 2 x 16B) — each thread covers row tid>>1, granules (tid&1)*2+{0,1}.
// MFMA frag maps (verified): A/B lane holds row/col (lane&15), k=(lane>>4)*8+i
// C/D: col=lane&15, row=(lane>>4)*4+reg.
// ===========================================================================

template <int ACT>  // 0=none, 1=relu
__global__ __launch_bounds__(256) void mfma_gemm(
    const float* __restrict__ A, int lda, int Ka,
    const unsigned short* __restrict__ B, int Kp,
    const float* __restrict__ bias, float* __restrict__ C, int Nout) {
  __shared__ unsigned short ldsA[128 * 32];
  __shared__ unsigned short ldsB[128 * 32];
  const int tid = threadIdx.x;
  const int n0 = blockIdx.x * 128;
  const int m0 = blockIdx.y * 128;

  // A staging: thread covers row=tid>>1, k-half=(tid&1)*16 (granules 2t, 2t+1)
  const int arow = tid >> 1;
  const int ahalf = (tid & 1) << 4;
  const int ag = (tid & 1) << 1;
  const int aswz = (arow >> 1) & 3;
  unsigned short* awp0 = &ldsA[((size_t)arow * 4 + ((ag | 0) ^ aswz)) * 8];
  unsigned short* awp1 = &ldsA[((size_t)arow * 4 + ((ag | 1) ^ aswz)) * 8];
  const float* aptr = A + (size_t)(m0 + arow) * lda;

  // B staging: same structure as A, from pre-cast bf16 global
  unsigned short* bwp0 = &ldsB[((size_t)arow * 4 + ((ag | 0) ^ aswz)) * 8];
  unsigned short* bwp1 = &ldsB[((size_t)arow * 4 + ((ag | 1) ^ aswz)) * 8];
  const unsigned short* bptr = B + (size_t)(n0 + arow) * Kp + ag * 8;

  const int lane = tid & 63;
  const int wave = tid >> 6;
  const int wm = (wave >> 1) << 6;
  const int wn = (wave & 1) << 6;
  const int r16 = lane & 15;
  const int kq = lane >> 4;

  const unsigned short* afp[4];
  const unsigned short* bfp[4];
#pragma unroll
  for (int i = 0; i < 4; i++) {
    int rowA = wm + i * 16 + r16;
    afp[i] = &ldsA[((size_t)rowA * 4 + (kq ^ ((rowA >> 1) & 3))) * 8];
    int rowB = wn + i * 16 + r16;
    bfp[i] = &ldsB[((size_t)rowB * 4 + (kq ^ ((rowB >> 1) & 3))) * 8];
  }

  f32x4 acc[4][4] = {};

  for (int k0 = 0; k0 < Kp; k0 += 32) {
    float4 f[4];
#pragma unroll
    for (int q = 0; q < 4; q++) {
      int k = k0 + ahalf + q * 4;
      if (k < Ka) f[q] = *(const float4*)(aptr + k);
      else f[q] = make_float4(0.f, 0.f, 0.f, 0.f);
    }
    uint4 w0, w1;
    w0.x = pack2bf(f[0].x, f[0].y); w0.y = pack2bf(f[0].z, f[0].w);
    w0.z = pack2bf(f[1].x, f[1].y); w0.w = pack2bf(f[1].z, f[1].w);
    w1.x = pack2bf(f[2].x, f[2].y); w1.y = pack2bf(f[2].z, f[2].w);
    w1.z = pack2bf(f[3].x, f[3].y); w1.w = pack2bf(f[3].z, f[3].w);
    uint4 bv0 = *(const uint4*)(bptr + k0);
    uint4 bv1 = *(const uint4*)(bptr + k0 + 8);
    *(uint4*)awp0 = w0;
    *(uint4*)awp1 = w1;
    *(uint4*)bwp0 = bv0;
    *(uint4*)bwp1 = bv1;
    __syncthreads();
    bf16x8 a[4], b[4];
#pragma unroll
    for (int i = 0; i < 4; i++) a[i] = *(const bf16x8*)afp[i];
#pragma unroll
    for (int i = 0; i < 4; i++) b[i] = *(const bf16x8*)bfp[i];
#pragma unroll
    for (int i = 0; i < 4; i++)
#pragma unroll
      for (int j = 0; j < 4; j++)
        acc[i][j] = __builtin_amdgcn_mfma_f32_16x16x32_bf16(a[i], b[j], acc[i][j], 0, 0, 0);
    __syncthreads();
  }

#pragma unroll
  for (int j = 0; j < 4; j++) {
    int n = n0 + wn + j * 16 + r16;
    if (n >= Nout) continue;
    float bi = bias[n];
#pragma unroll
    for (int i = 0; i < 4; i++) {
#pragma unroll
      for (int r = 0; r < 4; r++) {
        int m = m0 + wm + i * 16 + kq * 4 + r;
        float v = acc[i][j][r] + bi;
        if (ACT == 1) v = fmaxf(v, 0.f);
        C[(size_t)m * Nout + n] = v;
      }
    }
  }
}

// ---------------------------------------------------------------------------
// Embedding MFMA GEMM: 6 groups in one row space, tanh epilogue + scatter.
//   [0,4096) txt -> S[0], [4096,8192) vis -> S[1], [8192,12288) usr -> S[2],
//   [12288,53248) rt -> atomic S[3] (+E0 rows 0-9),
//   [53248,94208) rv -> atomic S[4] (+E0 rows 10-19),
//   [94208,135168) ru -> atomic S[5].
// ---------------------------------------------------------------------------
struct EmbedArgs {
  const float* A[6];
  const float* bias[6];
};

__global__ __launch_bounds__(256) void embed_mfma(
    EmbedArgs ea, const unsigned short* __restrict__ Wbf,
    float* __restrict__ S, float* __restrict__ E0) {
  __shared__ unsigned short ldsA[128 * 32];
  __shared__ unsigned short ldsB[128 * 32];
  const int tid = threadIdx.x;
  const int n0 = blockIdx.x * 128;
  const int m0 = blockIdx.y * 128;

  int g, base;
  if (m0 < 4096) { g = 0; base = 0; }
  else if (m0 < 8192) { g = 1; base = 4096; }
  else if (m0 < 12288) { g = 2; base = 8192; }
  else if (m0 < 53248) { g = 3; base = 12288; }
  else if (m0 < 94208) { g = 4; base = 53248; }
  else { g = 5; base = 94208; }

  const int arow = tid >> 1;
  const int ahalf = (tid & 1) << 4;
  const int ag = (tid & 1) << 1;
  const int aswz = (arow >> 1) & 3;
  unsigned short* awp0 = &ldsA[((size_t)arow * 4 + ((ag | 0) ^ aswz)) * 8];
  unsigned short* awp1 = &ldsA[((size_t)arow * 4 + ((ag | 1) ^ aswz)) * 8];
  const float* aptr = ea.A[g] + (size_t)(m0 - base + arow) * FD;

  unsigned short* bwp0 = &ldsB[((size_t)arow * 4 + ((ag | 0) ^ aswz)) * 8];
  unsigned short* bwp1 = &ldsB[((size_t)arow * 4 + ((ag | 1) ^ aswz)) * 8];
  const unsigned short* bptr =
      Wbf + (size_t)g * 512 * FD + (size_t)(n0 + arow) * FD + ag * 8;

  const int lane = tid & 63;
  const int wave = tid >> 6;
  const int wm = (wave >> 1) << 6;
  const int wn = (wave & 1) << 6;
  const int r16 = lane & 15;
  const int kq = lane >> 4;

  const unsigned short* afp[4];
  const unsigned short* bfp[4];
#pragma unroll
  for (int i = 0; i < 4; i++) {
    int rowA = wm + i * 16 + r16;
    afp[i] = &ldsA[((size_t)rowA * 4 + (kq ^ ((rowA >> 1) & 3))) * 8];
    int rowB = wn + i * 16 + r16;
    bfp[i] = &ldsB[((size_t)rowB * 4 + (kq ^ ((rowB >> 1) & 3))) * 8];
  }

  f32x4 acc[4][4] = {};

  for (int k0 = 0; k0 < FD; k0 += 32) {
    float4 f[4];
#pragma unroll
    for (int q = 0; q < 4; q++) f[q] = *(const float4*)(aptr + k0 + ahalf + q * 4);
    uint4 w0, w1;
    w0.x = pack2bf(f[0].x, f[0].y); w0.y = pack2bf(f[0].z, f[0].w);
    w0.z = pack2bf(f[1].x, f[1].y); w0.w = pack2bf(f[1].z, f[1].w);
    w1.x = pack2bf(f[2].x, f[2].y); w1.y = pack2bf(f[2].z, f[2].w);
    w1.z = pack2bf(f[3].x, f[3].y); w1.w = pack2bf(f[3].z, f[3].w);
    uint4 bv0 = *(const uint4*)(bptr + k0);
    uint4 bv1 = *(const uint4*)(bptr + k0 + 8);
    *(uint4*)awp0 = w0;
    *(uint4*)awp1 = w1;
    *(uint4*)bwp0 = bv0;
    *(uint4*)bwp1 = bv1;
    __syncthreads();
    bf16x8 a[4], b[4];
#pragma unroll
    for (int i = 0; i < 4; i++) a[i] = *(const bf16x8*)afp[i];
#pragma unroll
    for (int i = 0; i < 4; i++) b[i] = *(const bf16x8*)bfp[i];
#pragma unroll
    for (int i = 0; i < 4; i++)
#pragma unroll
      for (int j = 0; j < 4; j++)
        acc[i][j] = __builtin_amdgcn_mfma_f32_16x16x32_bf16(a[i], b[j], acc[i][j], 0, 0, 0);
    __syncthreads();
  }

  const float* bias = ea.bias[g];
#pragma unroll
  for (int j = 0; j < 4; j++) {
    int n = n0 + wn + j * 16 + r16;
    if (n >= PD) continue;
    float bi = bias[n];
#pragma unroll
    for (int i = 0; i < 4; i++) {
#pragma unroll
      for (int r = 0; r < 4; r++) {
        int m = m0 + wm + i * 16 + kq * 4 + r;
        int rl = m - base;
        float v = tanhf(acc[i][j][r] + bi);
        if (g < 3) {
          S[((size_t)g * BS + rl) * PD + n] = v;
        } else {
          int bb = rl / 10;
          int rr = rl - bb * 10;
          atomicAdd(&S[((size_t)g * BS + bb) * PD + n], v);
          if (g != 5 && bb == 0) E0[((size_t)(g - 3) * 10 + rr) * PD + n] = v;
        }
      }
    }
  }
}

// ---------------------------------------------------------------------------
// Edge means (fp32): Mn[b*4+e][k]
// ---------------------------------------------------------------------------
__global__ __launch_bounds__(256) void means_kernel(
    const float* __restrict__ S, float* __restrict__ Mn) {
  const int total = 4 * BS * PD;
  for (int i = blockIdx.x * blockDim.x + threadIdx.x; i < total;
       i += gridDim.x * blockDim.x) {
    int m = i / PD;
    int k = i - m * PD;
    int b = m >> 2, e = m & 3;
    float v;
    const size_t o = (size_t)b * PD + k;
    if (e == 0)
      v = (S[o] + S[(size_t)BS * PD + o] + S[2 * (size_t)BS * PD + o]) * (1.f / 3.f);
    else if (e == 1)
      v = (S[3 * (size_t)BS * PD + o] + S[o]) * (1.f / 11.f);
    else if (e == 2)
      v = (S[4 * (size_t)BS * PD + o] + S[(size_t)BS * PD + o]) * (1.f / 11.f);
    else
      v = (S[5 * (size_t)BS * PD + o] + S[2 * (size_t)BS * PD + o]) * (1.f / 11.f);
    Mn[i] = v;
  }
}

// ---------------------------------------------------------------------------
__global__ __launch_bounds__(256) void xte_kernel(
    const float* __restrict__ E0, const float* __restrict__ hg_w,
    const float* __restrict__ hg_b, float* __restrict__ XtE) {
  const int i = blockIdx.x;  // 0..19
  __shared__ float row[PD];
  for (int k = threadIdx.x; k < PD; k += 256) row[k] = E0[(size_t)i * PD + k];
  __syncthreads();
  for (int n = threadIdx.x; n < ZD; n += 256) {
    float s = 0.f;
    const float* w = hg_w + (size_t)n * PD;
    for (int k = 0; k < PD; k++) s += row[k] * w[k];
    XtE[(size_t)i * ZD + n] = s + hg_b[n];
  }
}

// ---------------------------------------------------------------------------
__global__ __launch_bounds__(256) void feat_kernel(
    const float* __restrict__ Y, const float* __restrict__ XtE,
    const float* __restrict__ sim_in, const float* __restrict__ label,
    const float* __restrict__ lbl_w, const float* __restrict__ lbl_b,
    float* __restrict__ feat) {
  const int b = blockIdx.x;
  __shared__ float w[RNUM];
  __shared__ float lbl_agg_s;
  if (threadIdx.x == 0) {
    float s[RNUM], mx = -1e30f;
    for (int r = 0; r < RNUM; r++) {
      s[r] = sim_in[(size_t)b * RNUM + r];
      mx = fmaxf(mx, s[r]);
    }
    float sum = 0.f;
    for (int r = 0; r < RNUM; r++) { s[r] = expf(s[r] - mx); sum += s[r]; }
    float la = 0.f;
    for (int r = 0; r < RNUM; r++) {
      w[r] = s[r] / sum;
      la += w[r] * label[(size_t)b * RNUM + r];
    }
    lbl_agg_s = la;
  }
  __syncthreads();
  const float* Yb = Y + (size_t)b * 4 * ZD;
  float* fb = feat + (size_t)b * 7 * ZD;
  const float la = lbl_agg_s;
  for (int n = threadIdx.x; n < ZD; n += blockDim.x) {
    float y0 = Yb[n], y1 = Yb[ZD + n], y2 = Yb[2 * ZD + n], y3 = Yb[3 * ZD + n];
    fb[n] = fmaxf(0.5f * (y0 + y1), 0.f);
    fb[ZD + n] = fmaxf(0.5f * (y0 + y2), 0.f);
    fb[2 * ZD + n] = fmaxf(0.5f * (y0 + y3), 0.f);
    float rv, rt;
    if (b == 0) {
      rv = 0.f; rt = 0.f;
      for (int r = 0; r < RNUM; r++) {
        float yp = 0.5f * (XtE[(size_t)r * ZD + n] + XtE[(size_t)(10 + r) * ZD + n]);
        rt += w[r] * fmaxf(0.5f * (y1 + yp), 0.f);
        rv += w[r] * fmaxf(0.5f * (y2 + yp), 0.f);
      }
    } else {
      rt = fmaxf(y1, 0.f);
      rv = fmaxf(y2, 0.f);
    }
    fb[3 * ZD + n] = rv;
    fb[4 * ZD + n] = rt;
    fb[5 * ZD + n] = fmaxf(y3, 0.f);
    fb[6 * ZD + n] = fmaxf(la * lbl_w[n] + lbl_b[n], 0.f);
  }
}

// ---------------------------------------------------------------------------
__global__ __launch_bounds__(256) void head_kernel(
    const float* __restrict__ h2, const float* __restrict__ p3_w,
    const float* __restrict__ p3_b, float* __restrict__ out) {
  const int wave = (blockIdx.x * blockDim.x + threadIdx.x) >> 6;
  const int lane = threadIdx.x & 63;
  if (wave >= BS) return;
  const float* row = h2 + (size_t)wave * 200;
  float s = 0.f;
  for (int k = lane; k < 200; k += 64) s += row[k] * p3_w[k];
#pragma unroll
  for (int off = 32; off; off >>= 1) s += __shfl_down(s, off, 64);
  if (lane == 0) out[wave] = 1.f / (1.f + expf(-(s + p3_b[0])));
}

// ---------------------------------------------------------------------------
extern "C" void kernel_launch(void* const* d_in, const int* in_sizes, int n_in,
                              void* d_out, int out_size, void* d_ws,
                              size_t ws_size, hipStream_t stream) {
  (void)in_sizes; (void)n_in; (void)out_size; (void)ws_size;

  const float* visual = (const float*)d_in[0];
  const float* textual = (const float*)d_in[1];
  const float* similarity = (const float*)d_in[2];
  const float* r_visual = (const float*)d_in[3];
  const float* r_textual = (const float*)d_in[4];
  const float* r_label = (const float*)d_in[5];
  const float* user = (const float*)d_in[6];
  const float* r_user = (const float*)d_in[7];
  const float* vis_w = (const float*)d_in[9];
  const float* vis_b = (const float*)d_in[10];
  const float* txt_w = (const float*)d_in[11];
  const float* txt_b = (const float*)d_in[12];
  const float* usr_w = (const float*)d_in[13];
  const float* usr_b = (const float*)d_in[14];
  const float* rvis_w = (const float*)d_in[15];
  const float* rvis_b = (const float*)d_in[16];
  const float* rtxt_w = (const float*)d_in[17];
  const float* rtxt_b = (const float*)d_in[18];
  const float* rusr_w = (const float*)d_in[19];
  const float* rusr_b = (const float*)d_in[20];
  const float* hg_w = (const float*)d_in[21];
  const float* hg_b = (const float*)d_in[22];
  const float* lbl_w = (const float*)d_in[23];
  const float* lbl_b = (const float*)d_in[24];
  const float* p1_w = (const float*)d_in[25];
  const float* p1_b = (const float*)d_in[26];
  const float* p2_w = (const float*)d_in[27];
  const float* p2_b = (const float*)d_in[28];
  const float* p3_w = (const float*)d_in[29];
  const float* p3_b = (const float*)d_in[30];
  float* out = (float*)d_out;

  // workspace layout
  float* ws = (float*)d_ws;
  float* S = ws;                            // 6*4096*500
  float* E0 = S + (size_t)6 * BS * PD;      // 20*500
  float* XtE = E0 + 20 * PD;                // 20*300
  float* Mn = XtE + 20 * ZD;                // 16384*500
  float* Y = Mn + (size_t)4 * BS * PD;      // 16384*300
  float* feat = Y + (size_t)4 * BS * ZD;    // 4096*2100
  float* h1 = feat + (size_t)BS * 7 * ZD;   // 4096*800
  float* h2 = h1 + (size_t)BS * 800;        // 4096*200
  unsigned short* Wbf = (unsigned short*)(h2 + (size_t)BS * 200);  // 6*512*768
  unsigned short* hgwbf = Wbf + (size_t)6 * 512 * FD;              // 384*512
  unsigned short* p1wbf = hgwbf + (size_t)384 * 512;               // 896*2112

  // pre-cast weights to zero-padded bf16
  const float* ew[6] = {txt_w, vis_w, usr_w, rtxt_w, rvis_w, rusr_w};
  for (int g = 0; g < 6; g++) {
    padcast<<<(512 * FD + 255) / 256, 256, 0, stream>>>(
        ew[g], Wbf + (size_t)g * 512 * FD, PD, FD, 512, FD);
  }
  padcast<<<(384 * 512 + 255) / 256, 256, 0, stream>>>(hg_w, hgwbf, ZD, PD, 384, 512);
  padcast<<<(896 * 2112 + 255) / 256, 256, 0, stream>>>(p1_w, p1wbf, 800, 2100, 896, 2112);

  hipMemsetAsync(S + (size_t)3 * BS * PD, 0, (size_t)3 * BS * PD * sizeof(float),
                 stream);

  EmbedArgs ea;
  ea.A[0] = textual;  ea.bias[0] = txt_b;
  ea.A[1] = visual;   ea.bias[1] = vis_b;
  ea.A[2] = user;     ea.bias[2] = usr_b;
  ea.A[3] = r_textual; ea.bias[3] = rtxt_b;
  ea.A[4] = r_visual;  ea.bias[4] = rvis_b;
  ea.A[5] = r_user;    ea.bias[5] = rusr_b;

  // grid: N-tiles fastest so blocks sharing an A M-tile are adjacent (L2 reuse)
  embed_mfma<<<dim3(4, 135168 / 128), 256, 0, stream>>>(ea, Wbf, S, E0);
  xte_kernel<<<20, 256, 0, stream>>>(E0, hg_w, hg_b, XtE);
  means_kernel<<<4096, 256, 0, stream>>>(S, Mn);
  mfma_gemm<0><<<dim3(3, 16384 / 128), 256, 0, stream>>>(
      Mn, PD, PD, hgwbf, 512, hg_b, Y, ZD);
  feat_kernel<<<BS, 256, 0, stream>>>(Y, XtE, similarity, r_label, lbl_w, lbl_b,
                                      feat);
  mfma_gemm<1><<<dim3(7, BS / 128), 256, 0, stream>>>(
      feat, 2100, 2100, p1wbf, 2112, p1_b, h1, 800);
  gemm_kernel<1><<<dim3(BS / BM, (200 + BN - 1) / BN), 256, 0, stream>>>(
      h1, p2_w, p2_b, h2, BS, 200, 800);
  head_kernel<<<BS * 64 / 256, 256, 0, stream>>>(h2, p3_w, p3_b, out);
}